// Round 7
// baseline (345.689 us; speedup 1.0000x reference)
//
#include <hip/hip_runtime.h>
#include <hip/hip_bf16.h>
#include <stdint.h>

// EdgeMLP: out[e] = relu(relu(concat(h1[src],h1[dst],h2[src],h2[dst]) @ W0 + b0) @ W1 + b1) @ W2 + b2
// Round 7: occupancy push. 32-edge tiles / 512 threads; h=relu(u+w) written
// in-place into the w-half of sUW (no sH); deferred out-write (2 barriers/tile);
// LDS 33.8KB -> 3-4 blocks/CU (6-8 waves/SIMD). Gather structure (global_load_lds,
// both-sides XOR swizzle, dbuf, 1-tile window) unchanged from R5/R6.

typedef __attribute__((ext_vector_type(8))) __bf16 bf16x8;
typedef __attribute__((ext_vector_type(4))) __bf16 bf16x4;
typedef __attribute__((ext_vector_type(4))) float  floatx4;

__device__ inline floatx4 mfma16x16x32(bf16x8 a, bf16x8 b, floatx4 c) {
  return __builtin_amdgcn_mfma_f32_16x16x32_bf16(a, b, c, 0, 0, 0);
}

__device__ inline void bar_lds() {
  asm volatile("s_waitcnt lgkmcnt(0)" ::: "memory");
  __builtin_amdgcn_s_barrier();
}

// ---- prep: weight transforms (bf16, n-major) ----
__global__ void cvt_w_kernel(const float* __restrict__ W0, const float* __restrict__ W1,
                             __bf16* __restrict__ W1T, __bf16* __restrict__ W0uT,
                             __bf16* __restrict__ W0wT) {
  const int t = blockIdx.x * 256 + threadIdx.x;  // 192 * 256 = 49152
  if (t < 16384) {
    const int n = t >> 7, k = t & 127;
    W1T[t] = (__bf16)W1[k * 128 + n];
  } else if (t < 32768) {
    const int t2 = t - 16384;
    const int n = t2 >> 7, k2 = t2 & 127;
    const int row = (k2 < 64) ? k2 : 64 + k2;        // h1 | h2 src rows
    W0uT[t2] = (__bf16)W0[row * 128 + n];
  } else {
    const int t3 = t - 32768;
    const int n = t3 >> 7, k2 = t3 & 127;
    const int row = (k2 < 64) ? 64 + k2 : 128 + k2;  // h1 | h2 dst rows
    W0wT[t3] = (__bf16)W0[row * 128 + n];
  }
}

// ---- node phase: u[v] = W0u^T [h1|h2](v) + b0 ; w[v] = W0w^T [h1|h2](v) ----
__global__ __launch_bounds__(256, 4)
void node_uw_kernel(const float* __restrict__ h1, const float* __restrict__ h2,
                    const __bf16* __restrict__ W0uT, const __bf16* __restrict__ W0wT,
                    const float* __restrict__ b0,
                    __bf16* __restrict__ uTab, __bf16* __restrict__ wTab, int nNodes) {
  __shared__ char sN[64 * 256];  // [64 nodes][128 k2] bf16, XOR-swizzled rows
  const int tid = threadIdx.x;
  const int base = blockIdx.x * 64;

  {  // stage
    const int r = tid >> 2, q = tid & 3;
    const int node = base + r;
    const int swz = (r & 7) << 4;
#pragma unroll
    for (int ii = 0; ii < 4; ++ii) {
      const int c = q * 4 + ii;
      bf16x8 v;
      if (node < nNodes) {
        const float* sp = (c < 8) ? (h1 + (size_t)node * 64 + c * 8)
                                  : (h2 + (size_t)node * 64 + (c - 8) * 8);
        const float4 x = reinterpret_cast<const float4*>(sp)[0];
        const float4 y = reinterpret_cast<const float4*>(sp)[1];
        v[0] = (__bf16)x.x; v[1] = (__bf16)x.y; v[2] = (__bf16)x.z; v[3] = (__bf16)x.w;
        v[4] = (__bf16)y.x; v[5] = (__bf16)y.y; v[6] = (__bf16)y.z; v[7] = (__bf16)y.w;
      } else {
#pragma unroll
        for (int k = 0; k < 8; ++k) v[k] = (__bf16)0.f;
      }
      *reinterpret_cast<bf16x8*>(sN + r * 256 + ((c * 16) ^ swz)) = v;
    }
  }
  __syncthreads();

  const int lane = tid & 63;
  const int l15 = lane & 15;
  const int hi = lane >> 4;
  const int hi16 = hi * 16;
  const int wvU = __builtin_amdgcn_readfirstlane(tid >> 6);

  float b0c[2][4];
#pragma unroll
  for (int nt = 0; nt < 2; ++nt)
#pragma unroll
    for (int r = 0; r < 4; ++r) b0c[nt][r] = b0[wvU * 32 + nt * 16 + hi * 4 + r];

#pragma unroll
  for (int pass = 0; pass < 2; ++pass) {
    const __bf16* Wt = pass ? W0wT : W0uT;
    __bf16* Tab = pass ? wTab : uTab;
    const bf16x8* wp = reinterpret_cast<const bf16x8*>(Wt);
    bf16x8 wf[4][2];
#pragma unroll
    for (int kk = 0; kk < 4; ++kk) {
      wf[kk][0] = wp[(wvU * 32 + l15) * 16 + kk * 4 + hi];
      wf[kk][1] = wp[(wvU * 32 + 16 + l15) * 16 + kk * 4 + hi];
    }
    floatx4 acc[4][2];
#pragma unroll
    for (int mt = 0; mt < 4; ++mt) { acc[mt][0] = (floatx4)0.f; acc[mt][1] = (floatx4)0.f; }
#pragma unroll
    for (int kk = 0; kk < 4; ++kk) {
#pragma unroll
      for (int mt = 0; mt < 4; ++mt) {
        const int row = mt * 16 + l15;
        const bf16x8 a = *reinterpret_cast<const bf16x8*>(
            sN + row * 256 + ((kk * 64 + hi16) ^ ((row & 7) << 4)));
        acc[mt][0] = mfma16x16x32(wf[kk][0], a, acc[mt][0]);
        acc[mt][1] = mfma16x16x32(wf[kk][1], a, acc[mt][1]);
      }
    }
#pragma unroll
    for (int mt = 0; mt < 4; ++mt) {
      const int node = base + mt * 16 + l15;
      if (node < nNodes) {
#pragma unroll
        for (int nt = 0; nt < 2; ++nt) {
          bf16x4 pk;
#pragma unroll
          for (int r = 0; r < 4; ++r) {
            const float v = acc[mt][nt][r] + (pass ? 0.f : b0c[nt][r]);
            pk[r] = (__bf16)v;
          }
          *reinterpret_cast<bf16x4*>(Tab + (size_t)node * 128 + wvU * 32 + nt * 16 +
                                     hi * 4) = pk;
        }
      }
    }
  }
}

// ---- edge kernel: 512 threads, 32-edge tiles, 8 waves = 2M x 4N ----
__global__ __launch_bounds__(512, 6)
void edge_uw_kernel(const __bf16* __restrict__ uTab, const __bf16* __restrict__ wTab,
                    const int* __restrict__ srcI, const int* __restrict__ dstI,
                    const __bf16* __restrict__ W1T, const float* __restrict__ b1,
                    const float* __restrict__ W2, const float* __restrict__ b2,
                    float* __restrict__ out, int E, int nTiles) {
  // sUW: 2 x [32 edges][512B] (u-row 256B ++ w-row 256B), double-buffered,
  //      linear dest for global_load_lds; within each 256B half, logical 16B
  //      chunk j of row e stored at phys (j&8)|((j&7)^(e&7)); reads XOR byte
  //      offsets (<256) with (e&7)<<4. The add-pass overwrites the w-half
  //      in place with h = relu(u+w) (thread-private chunk read-then-write).
  // sRed: [2][32 edges][4 waves] f32 layer-2 partials (deferred out-write).
  __shared__ char sUW[2 * 32 * 512];
  __shared__ float sRed[2][32][4];

  const int tid = threadIdx.x;
  const int lane = tid & 63;
  const int l15 = lane & 15;
  const int hi = lane >> 4;
  const int hi16 = hi * 16;
  const int wvU = __builtin_amdgcn_readfirstlane(tid >> 6);  // 0..7
  const int wm = wvU >> 2;       // M half: edges [16*wm, 16*wm+16)
  const int wn = wvU & 3;        // N quarter: cols [32*wn, 32*wn+32)

  // gather role: this wave stages edges [4*wvU, 4*wvU+4)
  const int lhalf = lane >> 5;          // which of 2 edges per issue
  const int p31 = lane & 31;            // phys 16B chunk within the 512B row
  const int half = (p31 >> 4) & 1;      // 0 -> u[src], 1 -> w[dst]
  const int* gIdxTab = half ? dstI : srcI;
  const __bf16* gTab = half ? wTab : uTab;

  // ---- per-wave register weights: W1T cols [32*wn, 32*wn+32) ----
  bf16x8 w1f[4][2];
  const bf16x8* w1p = reinterpret_cast<const bf16x8*>(W1T);
#pragma unroll
  for (int kk = 0; kk < 4; ++kk) {
    w1f[kk][0] = w1p[(wn * 32 + l15) * 16 + kk * 4 + hi];
    w1f[kk][1] = w1p[(wn * 32 + 16 + l15) * 16 + kk * 4 + hi];
  }
  float b1c[2][4], w2c[2][4];
#pragma unroll
  for (int nt = 0; nt < 2; ++nt)
#pragma unroll
    for (int r = 0; r < 4; ++r) {
      const int n = wn * 32 + nt * 16 + hi * 4 + r;
      b1c[nt][r] = b1[n];
      w2c[nt][r] = W2[n];
    }
  const float b2v = b2[0];

  const int tstride = gridDim.x;

  auto loadIdx = [&](int (&d)[2], int tt2) {
    const bool valid = tt2 < nTiles;
#pragma unroll
    for (int i = 0; i < 2; ++i) {
      const int eLoc = wvU * 4 + i * 2 + lhalf;
      const int ge = tt2 * 32 + eLoc;
      d[i] = (valid && ge < E) ? gIdxTab[ge] : 0;
    }
  };

  auto issueGather = [&](int nb, const int (&idx2)[2]) {
#pragma unroll
    for (int i = 0; i < 2; ++i) {
      const int eLoc = wvU * 4 + i * 2 + lhalf;
      const int wc = (p31 & 8) | ((p31 & 7) ^ (eLoc & 7));  // within-half chunk
      const __bf16* g = gTab + (size_t)idx2[i] * 128 + wc * 8;
      char* l = sUW + nb * 16384 + wvU * 2048 + i * 1024;  // + lane*16 added by HW
      __builtin_amdgcn_global_load_lds(
          (const __attribute__((address_space(1))) void*)g,
          (__attribute__((address_space(3))) void*)l, 16, 0, 0);
    }
  };

  // ---- prologue ----
  const int tile0 = blockIdx.x;
  int idxA[2], idxB[2];
  loadIdx(idxA, tile0);
  issueGather(0, idxA);
  loadIdx(idxB, tile0 + tstride);
  int cur = 0;
  int prevBase = -1;

  for (int tt = tile0; tt < nTiles; tt += tstride) {
    __syncthreads();  // drains vmcnt: sUW[cur] gathered; orders sRed reuse

    // ---- deferred out-write for previous tile (overlaps this tile) ----
    if (prevBase >= 0 && tid < 32) {
      const int ge = prevBase + tid;
      if (ge < E) {
        const float4 v = *reinterpret_cast<const float4*>(&sRed[cur ^ 1][tid][0]);
        out[ge] = v.x + v.y + v.z + v.w + b2v;
      }
    }

    // prefetch next tile's gathers (other buffer) + next-next indices
    if (tt + tstride < nTiles) issueGather(cur ^ 1, idxB);
    loadIdx(idxA, tt + 2 * tstride);

    char* sUWc = sUW + cur * 16384;

    // ---- "layer 0": h = relu(u+w) written in place into the w-half ----
    {
      const int aR = tid >> 4;            // row 0..31
      const int c = tid & 15;             // 16B chunk 0..15
      char* rowp = sUWc + aR * 512;
      const int off = (c * 16) ^ ((aR & 7) << 4);
      const bf16x8 uu = *reinterpret_cast<const bf16x8*>(rowp + off);
      const bf16x8 ww = *reinterpret_cast<const bf16x8*>(rowp + 256 + off);
      bf16x8 hh;
#pragma unroll
      for (int k = 0; k < 8; ++k)
        hh[k] = (__bf16)fmaxf((float)uu[k] + (float)ww[k], 0.0f);
      *reinterpret_cast<bf16x8*>(rowp + 256 + off) = hh;
    }
    bar_lds();  // B2: h visible

    // ---- layer 1 (swapped): this wave's 16 edges x 32 cols ----
    floatx4 acc0 = (floatx4)0.f, acc1 = (floatx4)0.f;
    {
      const int row = wm * 16 + l15;
      const char* rowh = sUWc + row * 512 + 256;
      const int rswz = (row & 7) << 4;
#pragma unroll
      for (int kk = 0; kk < 4; ++kk) {
        const bf16x8 a =
            *reinterpret_cast<const bf16x8*>(rowh + ((kk * 64 + hi16) ^ rswz));
        acc0 = mfma16x16x32(w1f[kk][0], a, acc0);
        acc1 = mfma16x16x32(w1f[kk][1], a, acc1);
      }
    }

    // ---- layer 2: per-lane dot over 8 n, reduce across hi groups -> sRed ----
    {
      float pp = 0.f;
#pragma unroll
      for (int r = 0; r < 4; ++r) {
        pp += fmaxf(acc0[r] + b1c[0][r], 0.0f) * w2c[0][r];
        pp += fmaxf(acc1[r] + b1c[1][r], 0.0f) * w2c[1][r];
      }
      pp += __shfl_xor(pp, 16);
      pp += __shfl_xor(pp, 32);
      if (lane < 16) sRed[cur][wm * 16 + l15][wn] = pp;
    }

    prevBase = tt * 32;
    idxB[0] = idxA[0];
    idxB[1] = idxA[1];
    cur ^= 1;
  }

  // ---- final deferred out-write ----
  __syncthreads();
  if (prevBase >= 0 && tid < 32) {
    const int ge = prevBase + tid;
    if (ge < E) {
      const float4 v = *reinterpret_cast<const float4*>(&sRed[cur ^ 1][tid][0]);
      out[ge] = v.x + v.y + v.z + v.w + b2v;
    }
  }
}

// ---- correctness fallback (only if workspace too small) ----
__global__ void edge_mlp_fallback(const float* __restrict__ h1, const float* __restrict__ h2,
                                  const int* __restrict__ src, const int* __restrict__ dst,
                                  const float* __restrict__ W0, const float* __restrict__ b0,
                                  const float* __restrict__ W1, const float* __restrict__ b1,
                                  const float* __restrict__ W2, const float* __restrict__ b2,
                                  float* __restrict__ out, int E) {
  __shared__ float sa[256];
  __shared__ float sh[128];
  __shared__ float sr[128];
  const int e = blockIdx.x;
  if (e >= E) return;
  const int t = threadIdx.x;  // 128 threads
  const int is = src[e], id = dst[e];
  if (t < 64) { sa[t] = h1[is * 64 + t]; sa[128 + t] = h2[is * 64 + t]; }
  else { const int u = t - 64; sa[64 + u] = h1[id * 64 + u]; sa[192 + u] = h2[id * 64 + u]; }
  __syncthreads();
  float a0 = b0[t];
  for (int k = 0; k < 256; ++k) a0 += sa[k] * W0[k * 128 + t];
  sh[t] = fmaxf(a0, 0.f);
  __syncthreads();
  float a1 = b1[t];
  for (int k = 0; k < 128; ++k) a1 += sh[k] * W1[k * 128 + t];
  sr[t] = fmaxf(a1, 0.f) * W2[t];
  __syncthreads();
  if (t == 0) {
    float s = b2[0];
    for (int k = 0; k < 128; ++k) s += sr[k];
    out[e] = s;
  }
}

extern "C" void kernel_launch(void* const* d_in, const int* in_sizes, int n_in,
                              void* d_out, int out_size, void* d_ws, size_t ws_size,
                              hipStream_t stream) {
  const float* h1 = (const float*)d_in[0];
  const float* h2 = (const float*)d_in[1];
  const int* src = (const int*)d_in[2];
  const int* dst = (const int*)d_in[3];
  const float* W0 = (const float*)d_in[4];
  const float* b0 = (const float*)d_in[5];
  const float* W1 = (const float*)d_in[6];
  const float* b1 = (const float*)d_in[7];
  const float* W2 = (const float*)d_in[8];
  const float* b2 = (const float*)d_in[9];
  float* out = (float*)d_out;

  const int D = 64;
  const int nNodes = in_sizes[0] / D;
  const int E = in_sizes[2];

  char* ws = (char*)d_ws;
  __bf16* W1T = (__bf16*)(ws);                 // 32768 B
  __bf16* W0uT = (__bf16*)(ws + 32768);        // 32768 B
  __bf16* W0wT = (__bf16*)(ws + 65536);        // 32768 B
  const size_t tabBytes = (size_t)nNodes * 128 * sizeof(__bf16);
  __bf16* uTab = (__bf16*)(ws + 98304);
  __bf16* wTab = (__bf16*)(ws + 98304 + tabBytes);
  const bool useFast = ws_size >= 98304 + 2 * tabBytes;

  if (!useFast) {
    edge_mlp_fallback<<<dim3(E), dim3(128), 0, stream>>>(
        h1, h2, src, dst, W0, b0, W1, b1, W2, b2, out, E);
    return;
  }

  cvt_w_kernel<<<dim3(192), dim3(256), 0, stream>>>(W0, W1, W1T, W0uT, W0wT);
  node_uw_kernel<<<dim3((nNodes + 63) / 64), dim3(256), 0, stream>>>(
      h1, h2, W0uT, W0wT, b0, uTab, wTab, nNodes);

  const int nTiles = (E + 31) / 32;
  const int grid = nTiles < 1024 ? nTiles : 1024;  // up to 4 blocks/CU resident
  edge_uw_kernel<<<dim3(grid), dim3(512), 0, stream>>>(
      uTab, wTab, src, dst, W1T, b1, W2, b2, out, E, nTiles);
}

// Round 8
// 207.803 us; speedup vs baseline: 1.6635x; 1.6635x over previous
//
#include <hip/hip_runtime.h>
#include <hip/hip_bf16.h>
#include <stdint.h>

// EdgeMLP: out[e] = relu(relu(concat(h1[src],h1[dst],h2[src],h2[dst]) @ W0 + b0) @ W1 + b1) @ W2 + b2
// Round 8: R6 edge kernel verbatim (64-edge tiles, 512 thr, 80KB LDS, dbuf
// global_load_lds gather, both-sides XOR swizzle, 3 barriers/tile) + two-level
// edge bucketing by (src-group, dst-group) with XCD-pinned processing so each
// XCD's L2 holds its u/w table slices. Sort is a deterministic-output counting
// sort (per-block LDS histogram + 64 global cursors).

typedef __attribute__((ext_vector_type(8))) __bf16 bf16x8;
typedef __attribute__((ext_vector_type(4))) __bf16 bf16x4;
typedef __attribute__((ext_vector_type(4))) float  floatx4;

__device__ inline floatx4 mfma16x16x32(bf16x8 a, bf16x8 b, floatx4 c) {
  return __builtin_amdgcn_mfma_f32_16x16x32_bf16(a, b, c, 0, 0, 0);
}

__device__ inline void bar_lds() {
  asm volatile("s_waitcnt lgkmcnt(0)" ::: "memory");
  __builtin_amdgcn_s_barrier();
}

// ---- prep: weight transforms (bf16, n-major) ----
__global__ void cvt_w_kernel(const float* __restrict__ W0, const float* __restrict__ W1,
                             __bf16* __restrict__ W1T, __bf16* __restrict__ W0uT,
                             __bf16* __restrict__ W0wT) {
  const int t = blockIdx.x * 256 + threadIdx.x;  // 192 * 256 = 49152
  if (t < 16384) {
    const int n = t >> 7, k = t & 127;
    W1T[t] = (__bf16)W1[k * 128 + n];
  } else if (t < 32768) {
    const int t2 = t - 16384;
    const int n = t2 >> 7, k2 = t2 & 127;
    const int row = (k2 < 64) ? k2 : 64 + k2;        // h1 | h2 src rows
    W0uT[t2] = (__bf16)W0[row * 128 + n];
  } else {
    const int t3 = t - 32768;
    const int n = t3 >> 7, k2 = t3 & 127;
    const int row = (k2 < 64) ? 64 + k2 : 128 + k2;  // h1 | h2 dst rows
    W0wT[t3] = (__bf16)W0[row * 128 + n];
  }
}

// ---- node phase: u[v] = W0u^T [h1|h2](v) + b0 ; w[v] = W0w^T [h1|h2](v) ----
__global__ __launch_bounds__(256, 2)
void node_uw_kernel(const float* __restrict__ h1, const float* __restrict__ h2,
                    const __bf16* __restrict__ W0uT, const __bf16* __restrict__ W0wT,
                    const float* __restrict__ b0,
                    __bf16* __restrict__ uTab, __bf16* __restrict__ wTab, int nNodes) {
  __shared__ char sN[64 * 256];  // [64 nodes][128 k2] bf16, XOR-swizzled rows
  const int tid = threadIdx.x;
  const int base = blockIdx.x * 64;

  {  // stage
    const int r = tid >> 2, q = tid & 3;
    const int node = base + r;
    const int swz = (r & 7) << 4;
#pragma unroll
    for (int ii = 0; ii < 4; ++ii) {
      const int c = q * 4 + ii;
      bf16x8 v;
      if (node < nNodes) {
        const float* sp = (c < 8) ? (h1 + (size_t)node * 64 + c * 8)
                                  : (h2 + (size_t)node * 64 + (c - 8) * 8);
        const float4 x = reinterpret_cast<const float4*>(sp)[0];
        const float4 y = reinterpret_cast<const float4*>(sp)[1];
        v[0] = (__bf16)x.x; v[1] = (__bf16)x.y; v[2] = (__bf16)x.z; v[3] = (__bf16)x.w;
        v[4] = (__bf16)y.x; v[5] = (__bf16)y.y; v[6] = (__bf16)y.z; v[7] = (__bf16)y.w;
      } else {
#pragma unroll
        for (int k = 0; k < 8; ++k) v[k] = (__bf16)0.f;
      }
      *reinterpret_cast<bf16x8*>(sN + r * 256 + ((c * 16) ^ swz)) = v;
    }
  }
  __syncthreads();

  const int lane = tid & 63;
  const int l15 = lane & 15;
  const int hi = lane >> 4;
  const int hi16 = hi * 16;
  const int wvU = __builtin_amdgcn_readfirstlane(tid >> 6);

  float b0c[2][4];
#pragma unroll
  for (int nt = 0; nt < 2; ++nt)
#pragma unroll
    for (int r = 0; r < 4; ++r) b0c[nt][r] = b0[wvU * 32 + nt * 16 + hi * 4 + r];

#pragma unroll
  for (int pass = 0; pass < 2; ++pass) {
    const __bf16* Wt = pass ? W0wT : W0uT;
    __bf16* Tab = pass ? wTab : uTab;
    const bf16x8* wp = reinterpret_cast<const bf16x8*>(Wt);
    bf16x8 wf[4][2];
#pragma unroll
    for (int kk = 0; kk < 4; ++kk) {
      wf[kk][0] = wp[(wvU * 32 + l15) * 16 + kk * 4 + hi];
      wf[kk][1] = wp[(wvU * 32 + 16 + l15) * 16 + kk * 4 + hi];
    }
    floatx4 acc[4][2];
#pragma unroll
    for (int mt = 0; mt < 4; ++mt) { acc[mt][0] = (floatx4)0.f; acc[mt][1] = (floatx4)0.f; }
#pragma unroll
    for (int kk = 0; kk < 4; ++kk) {
#pragma unroll
      for (int mt = 0; mt < 4; ++mt) {
        const int row = mt * 16 + l15;
        const bf16x8 a = *reinterpret_cast<const bf16x8*>(
            sN + row * 256 + ((kk * 64 + hi16) ^ ((row & 7) << 4)));
        acc[mt][0] = mfma16x16x32(wf[kk][0], a, acc[mt][0]);
        acc[mt][1] = mfma16x16x32(wf[kk][1], a, acc[mt][1]);
      }
    }
#pragma unroll
    for (int mt = 0; mt < 4; ++mt) {
      const int node = base + mt * 16 + l15;
      if (node < nNodes) {
#pragma unroll
        for (int nt = 0; nt < 2; ++nt) {
          bf16x4 pk;
#pragma unroll
          for (int r = 0; r < 4; ++r) {
            const float v = acc[mt][nt][r] + (pass ? 0.f : b0c[nt][r]);
            pk[r] = (__bf16)v;
          }
          *reinterpret_cast<bf16x4*>(Tab + (size_t)node * 128 + wvU * 32 + nt * 16 +
                                     hi * 4) = pk;
        }
      }
    }
  }
}

// ---- bucketing: key = (src/q)*8 + dst/q, 64 buckets ----
__global__ void zero_cnt_kernel(int* __restrict__ cnt) {
  if (threadIdx.x < 64) cnt[threadIdx.x] = 0;
}

__global__ void hist_kernel(const int* __restrict__ src, const int* __restrict__ dst,
                            int* __restrict__ cnt, int E, int q) {
  __shared__ int lc[64];
  if (threadIdx.x < 64) lc[threadIdx.x] = 0;
  __syncthreads();
  const int base = blockIdx.x * 2048;
#pragma unroll
  for (int j = 0; j < 8; ++j) {
    const int e = base + threadIdx.x + j * 256;
    if (e < E) {
      const int k = (src[e] / q) * 8 + dst[e] / q;
      atomicAdd(&lc[k], 1);
    }
  }
  __syncthreads();
  if (threadIdx.x < 64 && lc[threadIdx.x]) atomicAdd(&cnt[threadIdx.x], lc[threadIdx.x]);
}

__global__ void scan_kernel(const int* __restrict__ cnt, int* __restrict__ offE,
                            int* __restrict__ cur) {
  if (threadIdx.x == 0) {
    int run = 0;
    for (int k = 0; k < 64; ++k) {
      offE[k] = run;
      cur[k] = run;
      run += cnt[k];
    }
    offE[64] = run;
  }
}

__global__ void scatter_kernel(const int* __restrict__ src, const int* __restrict__ dst,
                               int* __restrict__ cur, int* __restrict__ srcP,
                               int* __restrict__ dstP, int* __restrict__ eP,
                               int E, int q) {
  __shared__ int lc[64];
  __shared__ int gb[64];
  if (threadIdx.x < 64) lc[threadIdx.x] = 0;
  __syncthreads();
  const int base = blockIdx.x * 2048;
  int myk[8], myr[8], mys[8], myd[8];
#pragma unroll
  for (int j = 0; j < 8; ++j) {
    const int e = base + threadIdx.x + j * 256;
    myk[j] = -1;
    if (e < E) {
      const int s = src[e], d = dst[e];
      const int k = (s / q) * 8 + d / q;
      myr[j] = atomicAdd(&lc[k], 1);
      myk[j] = k; mys[j] = s; myd[j] = d;
    }
  }
  __syncthreads();
  if (threadIdx.x < 64) {
    const int c = lc[threadIdx.x];
    gb[threadIdx.x] = c ? atomicAdd(&cur[threadIdx.x], c) : 0;
  }
  __syncthreads();
#pragma unroll
  for (int j = 0; j < 8; ++j) {
    if (myk[j] >= 0) {
      const int pos = gb[myk[j]] + myr[j];
      srcP[pos] = mys[j];
      dstP[pos] = myd[j];
      eP[pos] = base + threadIdx.x + j * 256;
    }
  }
}

// ---- edge kernel: R6 structure; SORTED adds XCD-pinned ranges + out scatter ----
template <bool SORTED>
__global__ __launch_bounds__(512, 2)
void edge_uw_kernel(const __bf16* __restrict__ uTab, const __bf16* __restrict__ wTab,
                    const int* __restrict__ srcA, const int* __restrict__ dstA,
                    const int* __restrict__ eP, const int* __restrict__ offE,
                    const __bf16* __restrict__ W1T, const float* __restrict__ b1,
                    const float* __restrict__ W2, const float* __restrict__ b2,
                    float* __restrict__ out, int E) {
  __shared__ char sUW[2 * 64 * 512];
  __shared__ char sH[64 * 256];

  const int tid = threadIdx.x;
  const int lane = tid & 63;
  const int l15 = lane & 15;
  const int hi = lane >> 4;
  const int hi16 = hi * 16;
  const int wvU = __builtin_amdgcn_readfirstlane(tid >> 6);  // 0..7
  const int wm = wvU >> 2;       // M half: edges [32*wm, 32*wm+32)
  const int wn = wvU & 3;        // N quarter: cols [32*wn, 32*wn+32)

  // range this block sweeps
  int lo, hi_e, bOff, bStride;
  if (SORTED) {
    const int x = blockIdx.x & 7;        // XCD via round-robin dispatch
    bOff = blockIdx.x >> 3;
    bStride = gridDim.x >> 3;            // blocks per XCD
    lo = offE[x * 8];
    hi_e = offE[x * 8 + 8];
  } else {
    lo = 0; hi_e = E; bOff = blockIdx.x; bStride = gridDim.x;
  }

  // gather role: this wave stages edges [8*wvU, 8*wvU+8) of the tile
  const int lhalf = lane >> 5;          // which of 2 edges per issue
  const int p31 = lane & 31;            // phys 16B chunk within the 512B row
  const int half = (p31 >> 4) & 1;      // 0 -> u[src], 1 -> w[dst]
  const int* gIdxTab = half ? dstA : srcA;
  const __bf16* gTab = half ? wTab : uTab;

  // ---- per-wave register weights: W1T cols [32*wn, 32*wn+32) ----
  bf16x8 w1f[4][2];
  const bf16x8* w1p = reinterpret_cast<const bf16x8*>(W1T);
#pragma unroll
  for (int kk = 0; kk < 4; ++kk) {
    w1f[kk][0] = w1p[(wn * 32 + l15) * 16 + kk * 4 + hi];
    w1f[kk][1] = w1p[(wn * 32 + 16 + l15) * 16 + kk * 4 + hi];
  }
  float b1c[2][4], w2c[2][4];
#pragma unroll
  for (int nt = 0; nt < 2; ++nt)
#pragma unroll
    for (int r = 0; r < 4; ++r) {
      const int n = wn * 32 + nt * 16 + hi * 4 + r;
      b1c[nt][r] = b1[n];
      w2c[nt][r] = W2[n];
    }
  const float b2v = b2[0];

  auto loadIdx = [&](int (&d)[4], int ebase) {
#pragma unroll
    for (int i = 0; i < 4; ++i) {
      const int eLoc = wvU * 8 + i * 2 + lhalf;
      const int ge = ebase + eLoc;
      d[i] = (ge < hi_e) ? gIdxTab[ge] : 0;
    }
  };

  auto issueGather = [&](int nb, const int (&idx4)[4]) {
#pragma unroll
    for (int i = 0; i < 4; ++i) {
      const int eLoc = wvU * 8 + i * 2 + lhalf;
      const int wc = (p31 & 8) | ((p31 & 7) ^ (eLoc & 7));  // within-half chunk
      const __bf16* g = gTab + (size_t)idx4[i] * 128 + wc * 8;
      char* l = sUW + nb * 32768 + wvU * 4096 + i * 1024;  // + lane*16 added by HW
      __builtin_amdgcn_global_load_lds(
          (const __attribute__((address_space(1))) void*)g,
          (__attribute__((address_space(3))) void*)l, 16, 0, 0);
    }
  };

  // ---- prologue ----
  const int tb0 = lo + bOff * 64;
  const int tstep = bStride * 64;
  int idxA[4], idxB[4];
  loadIdx(idxA, tb0);
  issueGather(0, idxA);
  loadIdx(idxB, tb0 + tstep);
  int cur = 0;

  for (int tb = tb0; tb < hi_e; tb += tstep) {
    __syncthreads();  // drains vmcnt: sUW[cur] ready; orders sH/sRed reuse

    // prefetch next tile's gathers (other buffer) + next-next indices
    if (tb + tstep < hi_e) issueGather(cur ^ 1, idxB);
    loadIdx(idxA, tb + 2 * tstep);

    char* sUWc = sUW + cur * 32768;

    // ---- "layer 0": h = relu(u[src] + w[dst]) -> sH ----
    {
      const int aR = tid >> 3;            // row 0..63
      const int q = tid & 7;
      const int aswz = (aR & 7) << 4;
      const char* rowU = sUWc + aR * 512;
      char* rowH = sH + aR * 256;
#pragma unroll
      for (int ii = 0; ii < 2; ++ii) {
        const int c = q * 2 + ii;         // 16B chunk 0..15
        const int off = (c * 16) ^ aswz;
        const bf16x8 uu = *reinterpret_cast<const bf16x8*>(rowU + off);
        const bf16x8 ww = *reinterpret_cast<const bf16x8*>(rowU + 256 + off);
        bf16x8 hh;
#pragma unroll
        for (int k = 0; k < 8; ++k)
          hh[k] = (__bf16)fmaxf((float)uu[k] + (float)ww[k], 0.0f);
        *reinterpret_cast<bf16x8*>(rowH + off) = hh;
      }
    }
    bar_lds();  // B2: sUW[cur] consumed, sH visible

    // ---- layer 1 (swapped): this wave's 32 edges x 32 cols ----
    floatx4 acc2T[2][2];
#pragma unroll
    for (int mt = 0; mt < 2; ++mt) { acc2T[mt][0] = (floatx4)0.f; acc2T[mt][1] = (floatx4)0.f; }
#pragma unroll
    for (int kk = 0; kk < 4; ++kk) {
#pragma unroll
      for (int mt = 0; mt < 2; ++mt) {
        const int row = wm * 32 + mt * 16 + l15;
        const bf16x8 a = *reinterpret_cast<const bf16x8*>(
            sH + row * 256 + ((kk * 64 + hi16) ^ ((row & 7) << 4)));
        acc2T[mt][0] = mfma16x16x32(w1f[kk][0], a, acc2T[mt][0]);
        acc2T[mt][1] = mfma16x16x32(w1f[kk][1], a, acc2T[mt][1]);
      }
    }

    // ---- layer 2: per-lane dot over 8 n, reduce across hi groups ----
    float* sRedF = (float*)sUWc;  // overlay on consumed sUW[cur]
#pragma unroll
    for (int mt = 0; mt < 2; ++mt) {
      float pp = 0.f;
#pragma unroll
      for (int nt = 0; nt < 2; ++nt)
#pragma unroll
        for (int r = 0; r < 4; ++r)
          pp += fmaxf(acc2T[mt][nt][r] + b1c[nt][r], 0.0f) * w2c[nt][r];
      pp += __shfl_xor(pp, 16);
      pp += __shfl_xor(pp, 32);
      if (lane < 16) sRedF[(wm * 32 + mt * 16 + l15) * 4 + wn] = pp;
    }
    bar_lds();  // B3: partials visible

    if (tid < 64) {
      const int ge = tb + tid;
      if (ge < hi_e) {
        const float4 v = reinterpret_cast<const float4*>(sRedF)[tid];
        const float r = v.x + v.y + v.z + v.w + b2v;
        if (SORTED) out[eP[ge]] = r; else out[ge] = r;
      }
    }

#pragma unroll
    for (int i = 0; i < 4; ++i) idxB[i] = idxA[i];
    cur ^= 1;
  }
}

// ---- correctness fallback (only if workspace too small) ----
__global__ void edge_mlp_fallback(const float* __restrict__ h1, const float* __restrict__ h2,
                                  const int* __restrict__ src, const int* __restrict__ dst,
                                  const float* __restrict__ W0, const float* __restrict__ b0,
                                  const float* __restrict__ W1, const float* __restrict__ b1,
                                  const float* __restrict__ W2, const float* __restrict__ b2,
                                  float* __restrict__ out, int E) {
  __shared__ float sa[256];
  __shared__ float sh[128];
  __shared__ float sr[128];
  const int e = blockIdx.x;
  if (e >= E) return;
  const int t = threadIdx.x;  // 128 threads
  const int is = src[e], id = dst[e];
  if (t < 64) { sa[t] = h1[is * 64 + t]; sa[128 + t] = h2[is * 64 + t]; }
  else { const int u = t - 64; sa[64 + u] = h1[id * 64 + u]; sa[192 + u] = h2[id * 64 + u]; }
  __syncthreads();
  float a0 = b0[t];
  for (int k = 0; k < 256; ++k) a0 += sa[k] * W0[k * 128 + t];
  sh[t] = fmaxf(a0, 0.f);
  __syncthreads();
  float a1 = b1[t];
  for (int k = 0; k < 128; ++k) a1 += sh[k] * W1[k * 128 + t];
  sr[t] = fmaxf(a1, 0.f) * W2[t];
  __syncthreads();
  if (t == 0) {
    float s = b2[0];
    for (int k = 0; k < 128; ++k) s += sr[k];
    out[e] = s;
  }
}

extern "C" void kernel_launch(void* const* d_in, const int* in_sizes, int n_in,
                              void* d_out, int out_size, void* d_ws, size_t ws_size,
                              hipStream_t stream) {
  const float* h1 = (const float*)d_in[0];
  const float* h2 = (const float*)d_in[1];
  const int* src = (const int*)d_in[2];
  const int* dst = (const int*)d_in[3];
  const float* W0 = (const float*)d_in[4];
  const float* b0 = (const float*)d_in[5];
  const float* W1 = (const float*)d_in[6];
  const float* b1 = (const float*)d_in[7];
  const float* W2 = (const float*)d_in[8];
  const float* b2 = (const float*)d_in[9];
  float* out = (float*)d_out;

  const int D = 64;
  const int nNodes = in_sizes[0] / D;
  const int E = in_sizes[2];

  char* ws = (char*)d_ws;
  __bf16* W1T = (__bf16*)(ws);                 // 32768 B
  __bf16* W0uT = (__bf16*)(ws + 32768);        // 32768 B
  __bf16* W0wT = (__bf16*)(ws + 65536);        // 32768 B
  const size_t tabBytes = (size_t)nNodes * 128 * sizeof(__bf16);
  __bf16* uTab = (__bf16*)(ws + 98304);
  __bf16* wTab = (__bf16*)(ws + 98304 + tabBytes);
  size_t off = 98304 + 2 * tabBytes;
  int* srcP = (int*)(ws + off); off += (size_t)E * 4;
  int* dstP = (int*)(ws + off); off += (size_t)E * 4;
  int* ePrm = (int*)(ws + off); off += (size_t)E * 4;
  int* cnt  = (int*)(ws + off); off += 256;
  int* offE = (int*)(ws + off); off += 512;
  int* curC = (int*)(ws + off); off += 256;

  const bool useFast = ws_size >= 98304 + 2 * tabBytes;
  const bool useSort = ws_size >= off;

  if (!useFast) {
    edge_mlp_fallback<<<dim3(E), dim3(128), 0, stream>>>(
        h1, h2, src, dst, W0, b0, W1, b1, W2, b2, out, E);
    return;
  }

  cvt_w_kernel<<<dim3(192), dim3(256), 0, stream>>>(W0, W1, W1T, W0uT, W0wT);
  node_uw_kernel<<<dim3((nNodes + 63) / 64), dim3(256), 0, stream>>>(
      h1, h2, W0uT, W0wT, b0, uTab, wTab, nNodes);

  if (useSort) {
    const int q = (nNodes + 7) / 8;
    const int nChunk = (E + 2047) / 2048;
    zero_cnt_kernel<<<dim3(1), dim3(64), 0, stream>>>(cnt);
    hist_kernel<<<dim3(nChunk), dim3(256), 0, stream>>>(src, dst, cnt, E, q);
    scan_kernel<<<dim3(1), dim3(64), 0, stream>>>(cnt, offE, curC);
    scatter_kernel<<<dim3(nChunk), dim3(256), 0, stream>>>(src, dst, curC, srcP, dstP,
                                                           ePrm, E, q);
    edge_uw_kernel<true><<<dim3(512), dim3(512), 0, stream>>>(
        uTab, wTab, srcP, dstP, ePrm, offE, W1T, b1, W2, b2, out, E);
  } else {
    const int nTiles = (E + 63) / 64;
    const int grid = nTiles < 512 ? nTiles : 512;
    edge_uw_kernel<false><<<dim3(grid), dim3(512), 0, stream>>>(
        uTab, wTab, src, dst, nullptr, nullptr, W1T, b1, W2, b2, out, E);
  }
}

// Round 10
// 139.949 us; speedup vs baseline: 2.4701x; 1.4848x over previous
//
#include <hip/hip_runtime.h>
#include <hip/hip_bf16.h>
#include <stdint.h>

// EdgeMLP: out[e] = relu(relu(concat(h1[src],h1[dst],h2[src],h2[dst]) @ W0 + b0) @ W1 + b1) @ W2 + b2
// Round 10: R6 structure EXACTLY (64-edge tiles, 512 thr, sH staging, 3
// barriers/tile, sRed overlay on consumed sUW, dbuf global_load_lds gather,
// both-sides XOR swizzle, grid 512) + fp16 dtype swap only:
//   u/w/W1 tables fp16 -> packed f16 add-pass, f16 MFMA (f32 accum).
// R9's sync restructure (in-place h, deferred out, 2 barriers) reverted — it
// raced under graph replay.

typedef __attribute__((ext_vector_type(8))) __bf16 bf16x8;
typedef __attribute__((ext_vector_type(8))) _Float16 f16x8;
typedef __attribute__((ext_vector_type(4))) _Float16 f16x4;
typedef __attribute__((ext_vector_type(4))) float  floatx4;

__device__ inline floatx4 mfma_bf16(bf16x8 a, bf16x8 b, floatx4 c) {
  return __builtin_amdgcn_mfma_f32_16x16x32_bf16(a, b, c, 0, 0, 0);
}
__device__ inline floatx4 mfma_f16(f16x8 a, f16x8 b, floatx4 c) {
  return __builtin_amdgcn_mfma_f32_16x16x32_f16(a, b, c, 0, 0, 0);
}

__device__ inline void bar_lds() {
  asm volatile("s_waitcnt lgkmcnt(0)" ::: "memory");
  __builtin_amdgcn_s_barrier();
}

// ---- prep: weight transforms ----
// W1T (fp16) [n][k] = W1[k][n]; W0uT/W0wT (bf16, node-phase MFMA inputs)
__global__ void cvt_w_kernel(const float* __restrict__ W0, const float* __restrict__ W1,
                             _Float16* __restrict__ W1T, __bf16* __restrict__ W0uT,
                             __bf16* __restrict__ W0wT) {
  const int t = blockIdx.x * 256 + threadIdx.x;  // 192 * 256 = 49152
  if (t < 16384) {
    const int n = t >> 7, k = t & 127;
    W1T[t] = (_Float16)W1[k * 128 + n];
  } else if (t < 32768) {
    const int t2 = t - 16384;
    const int n = t2 >> 7, k2 = t2 & 127;
    const int row = (k2 < 64) ? k2 : 64 + k2;        // h1 | h2 src rows
    W0uT[t2] = (__bf16)W0[row * 128 + n];
  } else {
    const int t3 = t - 32768;
    const int n = t3 >> 7, k2 = t3 & 127;
    const int row = (k2 < 64) ? 64 + k2 : 128 + k2;  // h1 | h2 dst rows
    W0wT[t3] = (__bf16)W0[row * 128 + n];
  }
}

// ---- node phase: u[v] = W0u^T [h1|h2](v) + b0 ; w[v] = W0w^T [h1|h2](v) ----
// Tables stored as fp16.
__global__ __launch_bounds__(256, 2)
void node_uw_kernel(const float* __restrict__ h1, const float* __restrict__ h2,
                    const __bf16* __restrict__ W0uT, const __bf16* __restrict__ W0wT,
                    const float* __restrict__ b0,
                    _Float16* __restrict__ uTab, _Float16* __restrict__ wTab,
                    int nNodes) {
  __shared__ char sN[64 * 256];  // [64 nodes][128 k2] bf16, XOR-swizzled rows
  const int tid = threadIdx.x;
  const int base = blockIdx.x * 64;

  {  // stage
    const int r = tid >> 2, q = tid & 3;
    const int node = base + r;
    const int swz = (r & 7) << 4;
#pragma unroll
    for (int ii = 0; ii < 4; ++ii) {
      const int c = q * 4 + ii;
      bf16x8 v;
      if (node < nNodes) {
        const float* sp = (c < 8) ? (h1 + (size_t)node * 64 + c * 8)
                                  : (h2 + (size_t)node * 64 + (c - 8) * 8);
        const float4 x = reinterpret_cast<const float4*>(sp)[0];
        const float4 y = reinterpret_cast<const float4*>(sp)[1];
        v[0] = (__bf16)x.x; v[1] = (__bf16)x.y; v[2] = (__bf16)x.z; v[3] = (__bf16)x.w;
        v[4] = (__bf16)y.x; v[5] = (__bf16)y.y; v[6] = (__bf16)y.z; v[7] = (__bf16)y.w;
      } else {
#pragma unroll
        for (int k = 0; k < 8; ++k) v[k] = (__bf16)0.f;
      }
      *reinterpret_cast<bf16x8*>(sN + r * 256 + ((c * 16) ^ swz)) = v;
    }
  }
  __syncthreads();

  const int lane = tid & 63;
  const int l15 = lane & 15;
  const int hi = lane >> 4;
  const int hi16 = hi * 16;
  const int wvU = __builtin_amdgcn_readfirstlane(tid >> 6);

  float b0c[2][4];
#pragma unroll
  for (int nt = 0; nt < 2; ++nt)
#pragma unroll
    for (int r = 0; r < 4; ++r) b0c[nt][r] = b0[wvU * 32 + nt * 16 + hi * 4 + r];

#pragma unroll
  for (int pass = 0; pass < 2; ++pass) {
    const __bf16* Wt = pass ? W0wT : W0uT;
    _Float16* Tab = pass ? wTab : uTab;
    const bf16x8* wp = reinterpret_cast<const bf16x8*>(Wt);
    bf16x8 wf[4][2];
#pragma unroll
    for (int kk = 0; kk < 4; ++kk) {
      wf[kk][0] = wp[(wvU * 32 + l15) * 16 + kk * 4 + hi];
      wf[kk][1] = wp[(wvU * 32 + 16 + l15) * 16 + kk * 4 + hi];
    }
    floatx4 acc[4][2];
#pragma unroll
    for (int mt = 0; mt < 4; ++mt) { acc[mt][0] = (floatx4)0.f; acc[mt][1] = (floatx4)0.f; }
#pragma unroll
    for (int kk = 0; kk < 4; ++kk) {
#pragma unroll
      for (int mt = 0; mt < 4; ++mt) {
        const int row = mt * 16 + l15;
        const bf16x8 a = *reinterpret_cast<const bf16x8*>(
            sN + row * 256 + ((kk * 64 + hi16) ^ ((row & 7) << 4)));
        acc[mt][0] = mfma_bf16(wf[kk][0], a, acc[mt][0]);
        acc[mt][1] = mfma_bf16(wf[kk][1], a, acc[mt][1]);
      }
    }
#pragma unroll
    for (int mt = 0; mt < 4; ++mt) {
      const int node = base + mt * 16 + l15;
      if (node < nNodes) {
#pragma unroll
        for (int nt = 0; nt < 2; ++nt) {
          f16x4 pk;
#pragma unroll
          for (int r = 0; r < 4; ++r) {
            const float v = acc[mt][nt][r] + (pass ? 0.f : b0c[nt][r]);
            pk[r] = (_Float16)v;
          }
          *reinterpret_cast<f16x4*>(Tab + (size_t)node * 128 + wvU * 32 + nt * 16 +
                                    hi * 4) = pk;
        }
      }
    }
  }
}

// ---- edge kernel: 512 threads, 64-edge tiles, 8 waves = 2M x 4N (R6 struct) ----
__global__ __launch_bounds__(512, 2)
void edge_uw_kernel(const _Float16* __restrict__ uTab, const _Float16* __restrict__ wTab,
                    const int* __restrict__ srcI, const int* __restrict__ dstI,
                    const _Float16* __restrict__ W1T, const float* __restrict__ b1,
                    const float* __restrict__ W2, const float* __restrict__ b2,
                    float* __restrict__ out, int E, int nTiles) {
  // sUW: 2 x [64 edges][512B] (u-row 256B ++ w-row 256B) fp16, double-buffered,
  //      linear dest for global_load_lds; within each 256B half, logical 16B
  //      chunk j of row e stored at phys (j&8)|((j&7)^(e&7)); reads XOR byte
  //      offsets (<256) with (e&7)<<4.
  // sH : [64][128] fp16 rows of relu(u+w), 256B rows, same XOR swizzle.
  // sRed: overlay on head of consumed sUW[cur] (layer-2 partials, 1KB).
  __shared__ char sUW[2 * 64 * 512];
  __shared__ char sH[64 * 256];

  const int tid = threadIdx.x;
  const int lane = tid & 63;
  const int l15 = lane & 15;
  const int hi = lane >> 4;
  const int hi16 = hi * 16;
  const int wvU = __builtin_amdgcn_readfirstlane(tid >> 6);  // 0..7
  const int wm = wvU >> 2;       // M half: edges [32*wm, 32*wm+32)
  const int wn = wvU & 3;        // N quarter: cols [32*wn, 32*wn+32)

  // gather role: this wave stages edges [8*wvU, 8*wvU+8) of the tile
  const int lhalf = lane >> 5;          // which of 2 edges per issue
  const int p31 = lane & 31;            // phys 16B chunk within the 512B row
  const int half = (p31 >> 4) & 1;      // 0 -> u[src], 1 -> w[dst]
  const int* gIdxTab = half ? dstI : srcI;
  const _Float16* gTab = half ? wTab : uTab;

  // ---- per-wave register weights: W1T cols [32*wn, 32*wn+32) ----
  f16x8 w1f[4][2];
  const f16x8* w1p = reinterpret_cast<const f16x8*>(W1T);
#pragma unroll
  for (int kk = 0; kk < 4; ++kk) {
    w1f[kk][0] = w1p[(wn * 32 + l15) * 16 + kk * 4 + hi];
    w1f[kk][1] = w1p[(wn * 32 + 16 + l15) * 16 + kk * 4 + hi];
  }
  float b1c[2][4], w2c[2][4];
#pragma unroll
  for (int nt = 0; nt < 2; ++nt)
#pragma unroll
    for (int r = 0; r < 4; ++r) {
      const int n = wn * 32 + nt * 16 + hi * 4 + r;
      b1c[nt][r] = b1[n];
      w2c[nt][r] = W2[n];
    }
  const float b2v = b2[0];

  const int tstride = gridDim.x;

  auto loadIdx = [&](int (&d)[4], int tt2) {
    const bool valid = tt2 < nTiles;
#pragma unroll
    for (int i = 0; i < 4; ++i) {
      const int eLoc = wvU * 8 + i * 2 + lhalf;
      const int ge = tt2 * 64 + eLoc;
      d[i] = (valid && ge < E) ? gIdxTab[ge] : 0;
    }
  };

  auto issueGather = [&](int nb, const int (&idx4)[4]) {
#pragma unroll
    for (int i = 0; i < 4; ++i) {
      const int eLoc = wvU * 8 + i * 2 + lhalf;
      const int wc = (p31 & 8) | ((p31 & 7) ^ (eLoc & 7));  // within-half chunk
      const _Float16* g = gTab + (size_t)idx4[i] * 128 + wc * 8;
      char* l = sUW + nb * 32768 + wvU * 4096 + i * 1024;  // + lane*16 added by HW
      __builtin_amdgcn_global_load_lds(
          (const __attribute__((address_space(1))) void*)g,
          (__attribute__((address_space(3))) void*)l, 16, 0, 0);
    }
  };

  // ---- prologue ----
  const int tile0 = blockIdx.x;
  int idxA[4], idxB[4];
  loadIdx(idxA, tile0);
  issueGather(0, idxA);
  loadIdx(idxB, tile0 + tstride);
  int cur = 0;

  for (int tt = tile0; tt < nTiles; tt += tstride) {
    __syncthreads();  // drains vmcnt: sUW[cur] ready; orders sH/sRed reuse

    // prefetch next tile's gathers (other buffer) + next-next indices
    if (tt + tstride < nTiles) issueGather(cur ^ 1, idxB);
    loadIdx(idxA, tt + 2 * tstride);

    char* sUWc = sUW + cur * 32768;

    // ---- "layer 0": h = relu(u[src] + w[dst]) -> sH (packed f16) ----
    {
      const int aR = tid >> 3;            // row 0..63
      const int q = tid & 7;
      const int aswz = (aR & 7) << 4;
      const char* rowU = sUWc + aR * 512;
      char* rowH = sH + aR * 256;
#pragma unroll
      for (int ii = 0; ii < 2; ++ii) {
        const int c = q * 2 + ii;         // 16B chunk 0..15
        const int off = (c * 16) ^ aswz;
        const f16x8 uu = *reinterpret_cast<const f16x8*>(rowU + off);
        const f16x8 ww = *reinterpret_cast<const f16x8*>(rowU + 256 + off);
        f16x8 hh = uu + ww;               // v_pk_add_f16
#pragma unroll
        for (int k = 0; k < 8; ++k)
          hh[k] = hh[k] > (_Float16)0 ? hh[k] : (_Float16)0;  // packed max
        *reinterpret_cast<f16x8*>(rowH + off) = hh;
      }
    }
    bar_lds();  // B2: sUW[cur] consumed, sH visible

    // ---- layer 1 (swapped, f16): this wave's 32 edges x 32 cols ----
    floatx4 acc2T[2][2];
#pragma unroll
    for (int mt = 0; mt < 2; ++mt) { acc2T[mt][0] = (floatx4)0.f; acc2T[mt][1] = (floatx4)0.f; }
#pragma unroll
    for (int kk = 0; kk < 4; ++kk) {
#pragma unroll
      for (int mt = 0; mt < 2; ++mt) {
        const int row = wm * 32 + mt * 16 + l15;
        const f16x8 a = *reinterpret_cast<const f16x8*>(
            sH + row * 256 + ((kk * 64 + hi16) ^ ((row & 7) << 4)));
        acc2T[mt][0] = mfma_f16(w1f[kk][0], a, acc2T[mt][0]);
        acc2T[mt][1] = mfma_f16(w1f[kk][1], a, acc2T[mt][1]);
      }
    }

    // ---- layer 2: per-lane dot over 8 n, reduce across hi groups ----
    float* sRedF = (float*)sUWc;  // overlay on consumed sUW[cur]
#pragma unroll
    for (int mt = 0; mt < 2; ++mt) {
      float pp = 0.f;
#pragma unroll
      for (int nt = 0; nt < 2; ++nt)
#pragma unroll
        for (int r = 0; r < 4; ++r)
          pp += fmaxf(acc2T[mt][nt][r] + b1c[nt][r], 0.0f) * w2c[nt][r];
      pp += __shfl_xor(pp, 16);
      pp += __shfl_xor(pp, 32);
      if (lane < 16) sRedF[(wm * 32 + mt * 16 + l15) * 4 + wn] = pp;
    }
    bar_lds();  // B3: partials visible

    if (tid < 64) {
      const int ge = tt * 64 + tid;
      if (ge < E) {
        const float4 v = reinterpret_cast<const float4*>(sRedF)[tid];
        out[ge] = v.x + v.y + v.z + v.w + b2v;
      }
    }

#pragma unroll
    for (int i = 0; i < 4; ++i) idxB[i] = idxA[i];
    cur ^= 1;
  }
}

// ---- correctness fallback (only if workspace too small) ----
__global__ void edge_mlp_fallback(const float* __restrict__ h1, const float* __restrict__ h2,
                                  const int* __restrict__ src, const int* __restrict__ dst,
                                  const float* __restrict__ W0, const float* __restrict__ b0,
                                  const float* __restrict__ W1, const float* __restrict__ b1,
                                  const float* __restrict__ W2, const float* __restrict__ b2,
                                  float* __restrict__ out, int E) {
  __shared__ float sa[256];
  __shared__ float sh[128];
  __shared__ float sr[128];
  const int e = blockIdx.x;
  if (e >= E) return;
  const int t = threadIdx.x;  // 128 threads
  const int is = src[e], id = dst[e];
  if (t < 64) { sa[t] = h1[is * 64 + t]; sa[128 + t] = h2[is * 64 + t]; }
  else { const int u = t - 64; sa[64 + u] = h1[id * 64 + u]; sa[192 + u] = h2[id * 64 + u]; }
  __syncthreads();
  float a0 = b0[t];
  for (int k = 0; k < 256; ++k) a0 += sa[k] * W0[k * 128 + t];
  sh[t] = fmaxf(a0, 0.f);
  __syncthreads();
  float a1 = b1[t];
  for (int k = 0; k < 128; ++k) a1 += sh[k] * W1[k * 128 + t];
  sr[t] = fmaxf(a1, 0.f) * W2[t];
  __syncthreads();
  if (t == 0) {
    float s = b2[0];
    for (int k = 0; k < 128; ++k) s += sr[k];
    out[e] = s;
  }
}

extern "C" void kernel_launch(void* const* d_in, const int* in_sizes, int n_in,
                              void* d_out, int out_size, void* d_ws, size_t ws_size,
                              hipStream_t stream) {
  const float* h1 = (const float*)d_in[0];
  const float* h2 = (const float*)d_in[1];
  const int* src = (const int*)d_in[2];
  const int* dst = (const int*)d_in[3];
  const float* W0 = (const float*)d_in[4];
  const float* b0 = (const float*)d_in[5];
  const float* W1 = (const float*)d_in[6];
  const float* b1 = (const float*)d_in[7];
  const float* W2 = (const float*)d_in[8];
  const float* b2 = (const float*)d_in[9];
  float* out = (float*)d_out;

  const int D = 64;
  const int nNodes = in_sizes[0] / D;
  const int E = in_sizes[2];

  char* ws = (char*)d_ws;
  _Float16* W1T = (_Float16*)(ws);             // 32768 B
  __bf16* W0uT = (__bf16*)(ws + 32768);        // 32768 B
  __bf16* W0wT = (__bf16*)(ws + 65536);        // 32768 B
  const size_t tabBytes = (size_t)nNodes * 128 * sizeof(_Float16);
  _Float16* uTab = (_Float16*)(ws + 98304);
  _Float16* wTab = (_Float16*)(ws + 98304 + tabBytes);
  const bool useFast = ws_size >= 98304 + 2 * tabBytes;

  if (!useFast) {
    edge_mlp_fallback<<<dim3(E), dim3(128), 0, stream>>>(
        h1, h2, src, dst, W0, b0, W1, b1, W2, b2, out, E);
    return;
  }

  cvt_w_kernel<<<dim3(192), dim3(256), 0, stream>>>(W0, W1, W1T, W0uT, W0wT);
  node_uw_kernel<<<dim3((nNodes + 63) / 64), dim3(256), 0, stream>>>(
      h1, h2, W0uT, W0wT, b0, uTab, wTab, nNodes);

  const int nTiles = (E + 63) / 64;
  const int grid = nTiles < 512 ? nTiles : 512;  // 2 blocks/CU resident
  edge_uw_kernel<<<dim3(grid), dim3(512), 0, stream>>>(
      uTab, wTab, src, dst, W1T, b1, W2, b2, out, E, nTiles);
}